// Round 8
// baseline (237.792 us; speedup 1.0000x reference)
//
#include <hip/hip_runtime.h>
#include <math.h>

#define HD     64
#define NPIX   9216
#define B4     4
#define K9     9
#define QBLK   128           // queries per block (4 waves x 32)
#define KT     32            // keys per LDS tile
#define ZS     8             // key-split factor (main gate pass)
#define KQZ    (NPIX / ZS)   // 1152 keys per block
#define NTZ    (KQZ / KT)    // 36 tiles
#define SSL    2             // sample slices (tau from keys 0..2303)
#define DGATE  13.0f         // gate margin (scaled-score units)
#define THRM   3.0f          // exact-rescore margin (~17 sigma of bf16 score err)
#define CAP    80            // candidate slots per query

typedef __attribute__((ext_vector_type(8))) short bf16x8;
typedef __attribute__((ext_vector_type(4))) float f32x4;
typedef unsigned short ushort_t;

__device__ __forceinline__ ushort_t f2bf(float x) {
  unsigned u = __float_as_uint(x);
  unsigned r = (u + 0x7fffu + ((u >> 16) & 1u)) >> 16;   // RNE
  return (ushort_t)r;
}

// ---- prep: transpose [b][d][n] -> [b][n][d]; z=0: Qbf(x8); z=1: Kbf+Kt; z=2: Vt
__global__ __launch_bounds__(256) void prep_kernel(
    const float* __restrict__ qg, const float* __restrict__ kg,
    const float* __restrict__ vg,
    ushort_t* __restrict__ Qbf, ushort_t* __restrict__ Kbf,
    float* __restrict__ Kt, float* __restrict__ Vt) {
  __shared__ float Ts[64][65];
  const int b = blockIdx.y, n0 = blockIdx.x * 64, z = blockIdx.z;
  const float* src = (z == 0) ? qg : (z == 1) ? kg : vg;
  const int tid = threadIdx.x;
  #pragma unroll
  for (int i = 0; i < 16; ++i) {
    const int idx = i * 256 + tid, c = idx >> 6, nl = idx & 63;
    Ts[c][nl] = src[((size_t)b * HD + c) * NPIX + n0 + nl];
  }
  __syncthreads();
  if (z == 0) {
    #pragma unroll
    for (int i = 0; i < 16; ++i) {
      const int idx = i * 256 + tid, nl = idx >> 6, d = idx & 63;
      Qbf[((size_t)b * NPIX + n0 + nl) * HD + d] = f2bf(Ts[d][nl] * 8.f);
    }
  } else if (z == 1) {
    #pragma unroll
    for (int i = 0; i < 16; ++i) {
      const int idx = i * 256 + tid, nl = idx >> 6, d = idx & 63;
      const float x = Ts[d][nl];
      const size_t o = ((size_t)b * NPIX + n0 + nl) * HD + d;
      Kbf[o] = f2bf(x); Kt[o] = x;
    }
  } else {
    #pragma unroll
    for (int i = 0; i < 16; ++i) {
      const int idx = i * 256 + tid, nl = idx >> 6, d = idx & 63;
      Vt[((size_t)b * NPIX + n0 + nl) * HD + d] = Ts[d][nl];
    }
  }
}

// ---------------- async global -> LDS (16B per lane, linear dest) ------------
__device__ __forceinline__ void gl_lds16(const void* g, void* l) {
  auto gp = reinterpret_cast<const unsigned int __attribute__((address_space(1)))*>(
      reinterpret_cast<uintptr_t>(g));
  auto lp = reinterpret_cast<unsigned int __attribute__((address_space(3)))*>(
      reinterpret_cast<uintptr_t>(l));
  __builtin_amdgcn_global_load_lds(gp, lp, 16, 0, 0);
}

// ---- sorted-9 insert with (val desc, idx asc) tie-break ---------------------
__device__ __forceinline__ void ins9t(float (&tv)[K9], int (&ti)[K9], float s, int m) {
  float cv = s; int ci = m;
  #pragma unroll
  for (int r = 0; r < K9; ++r) {
    const bool c = (cv > tv[r]) || (cv == tv[r] && ci < ti[r]);
    const float hv = c ? cv : tv[r];  const float lv = c ? tv[r] : cv;
    const int   hk = c ? ci : ti[r];  const int   lk = c ? ti[r] : ci;
    tv[r] = hv; ti[r] = hk; cv = lv; ci = lk;
  }
}

// ==== sample pass: per-query max over keys [z*1152, z*1152+1152) =============
__global__ __launch_bounds__(256, 8) void pass_sample(
    const ushort_t* __restrict__ Qbf, const ushort_t* __restrict__ Kbf,
    float* __restrict__ Pm) {
  __shared__ __align__(16) char SM[2][4096];

  const int tid = threadIdx.x;
  const int w = tid >> 6, l = tid & 63, lg = l >> 4, lc = l & 15;
  const int b = blockIdx.y, qbase = blockIdx.x * QBLK, z = blockIdx.z;
  const int kbase = z * KQZ;

  const int qw = qbase + w * 32;
  const size_t qr0 = ((size_t)b * NPIX + qw + lc) * HD + lg * 8;
  const size_t qr1 = qr0 + (size_t)16 * HD;
  const bf16x8 q0h0 = *reinterpret_cast<const bf16x8*>(Qbf + qr0);
  const bf16x8 q0h1 = *reinterpret_cast<const bf16x8*>(Qbf + qr0 + 32);
  const bf16x8 q1h0 = *reinterpret_cast<const bf16x8*>(Qbf + qr1);
  const bf16x8 q1h1 = *reinterpret_cast<const bf16x8*>(Qbf + qr1 + 32);

  const char* kB = reinterpret_cast<const char*>(Kbf + (size_t)b * NPIX * HD);

  const int sr = tid >> 3, sc = tid & 7;
  const int srcoff = sr * 128 + ((sc ^ (sr & 7)) << 4);
  const int hdst = w * 1024;                       // wave-uniform LDS offset (FIX)
  const int o0 = ((lg ^ (lc & 7)) << 4);
  const int o1 = (((4 + lg) ^ (lc & 7)) << 4);

  auto stage = [&](int tile, int nb) {
    const size_t toff = ((size_t)(kbase + tile * KT)) * 128 + srcoff;
    gl_lds16(kB + toff, SM[nb] + hdst);
  };

  float m0 = -3.4e38f, m1 = -3.4e38f;
  stage(0, 0);
  __syncthreads();

  for (int t = 0; t < NTZ; ++t) {
    const int cur = t & 1;
    if (t + 1 < NTZ) stage(t + 1, cur ^ 1);
    const char* kt = SM[cur];
    #pragma unroll
    for (int s = 0; s < 2; ++s) {
      const int ro = (s * 16 + lc) * 128;
      const bf16x8 ah0 = *reinterpret_cast<const bf16x8*>(kt + ro + o0);
      const bf16x8 ah1 = *reinterpret_cast<const bf16x8*>(kt + ro + o1);
      f32x4 acc0 = {0.f, 0.f, 0.f, 0.f};
      f32x4 acc1 = {0.f, 0.f, 0.f, 0.f};
      acc0 = __builtin_amdgcn_mfma_f32_16x16x32_bf16(ah0, q0h0, acc0, 0, 0, 0);
      acc1 = __builtin_amdgcn_mfma_f32_16x16x32_bf16(ah0, q1h0, acc1, 0, 0, 0);
      acc0 = __builtin_amdgcn_mfma_f32_16x16x32_bf16(ah1, q0h1, acc0, 0, 0, 0);
      acc1 = __builtin_amdgcn_mfma_f32_16x16x32_bf16(ah1, q1h1, acc1, 0, 0, 0);
      m0 = fmaxf(m0, fmaxf(fmaxf(acc0[0], acc0[1]), fmaxf(acc0[2], acc0[3])));
      m1 = fmaxf(m1, fmaxf(fmaxf(acc1[0], acc1[1]), fmaxf(acc1[2], acc1[3])));
    }
    __syncthreads();
  }

  m0 = fmaxf(m0, __shfl_xor(m0, 16, 64));
  m0 = fmaxf(m0, __shfl_xor(m0, 32, 64));
  m1 = fmaxf(m1, __shfl_xor(m1, 16, 64));
  m1 = fmaxf(m1, __shfl_xor(m1, 32, 64));
  if (lg == 0) {
    Pm[((size_t)b * NPIX + qw + lc) * SSL + z]      = m0;
    Pm[((size_t)b * NPIX + qw + 16 + lc) * SSL + z] = m1;
  }
}

// ==== gate pass: hi-only scores, gate = max(tau_sample, m_run) - DGATE =======
__global__ __launch_bounds__(256, 8) void pass_gate(
    const ushort_t* __restrict__ Qbf, const ushort_t* __restrict__ Kbf,
    const float* __restrict__ Pm,
    int* __restrict__ Cnt, float2* __restrict__ Cand) {
  __shared__ __align__(16) char SM[2][4096];

  const int tid = threadIdx.x;
  const int w = tid >> 6, l = tid & 63, lg = l >> 4, lc = l & 15;
  const int b = blockIdx.y, qbase = blockIdx.x * QBLK, z = blockIdx.z;
  const int kbase = z * KQZ;

  const int qw = qbase + w * 32;
  const int qi0 = b * NPIX + qw + lc;
  const int qi1 = qi0 + 16;
  const size_t qr0 = ((size_t)b * NPIX + qw + lc) * HD + lg * 8;
  const size_t qr1 = qr0 + (size_t)16 * HD;
  const bf16x8 q0h0 = *reinterpret_cast<const bf16x8*>(Qbf + qr0);
  const bf16x8 q0h1 = *reinterpret_cast<const bf16x8*>(Qbf + qr0 + 32);
  const bf16x8 q1h0 = *reinterpret_cast<const bf16x8*>(Qbf + qr1);
  const bf16x8 q1h1 = *reinterpret_cast<const bf16x8*>(Qbf + qr1 + 32);

  // tau from sample max (keys 0..2303); m_run keeps it exact-safe everywhere
  const float tau0 = fmaxf(Pm[(size_t)qi0 * SSL], Pm[(size_t)qi0 * SSL + 1]);
  const float tau1 = fmaxf(Pm[(size_t)qi1 * SSL], Pm[(size_t)qi1 * SSL + 1]);

  const char* kB = reinterpret_cast<const char*>(Kbf + (size_t)b * NPIX * HD);

  const int sr = tid >> 3, sc = tid & 7;
  const int srcoff = sr * 128 + ((sc ^ (sr & 7)) << 4);
  const int hdst = w * 1024;                       // wave-uniform LDS offset (FIX)
  const int o0 = ((lg ^ (lc & 7)) << 4);
  const int o1 = (((4 + lg) ^ (lc & 7)) << 4);

  auto stage = [&](int tile, int nb) {
    const size_t toff = ((size_t)(kbase + tile * KT)) * 128 + srcoff;
    gl_lds16(kB + toff, SM[nb] + hdst);
  };

  auto emit = [&](float s, int m, int qi) {
    const int slot = atomicAdd(&Cnt[qi], 1);
    if (slot < CAP) Cand[(size_t)qi * CAP + slot] = make_float2(s, __int_as_float(m));
  };

  float m0 = tau0, m1 = tau1;   // running max seeded with sample max
  stage(0, 0);
  __syncthreads();

  for (int t = 0; t < NTZ; ++t) {
    const int cur = t & 1;
    if (t + 1 < NTZ) stage(t + 1, cur ^ 1);
    const char* kt = SM[cur];

    #pragma unroll
    for (int s = 0; s < 2; ++s) {
      const int ro = (s * 16 + lc) * 128;
      const bf16x8 ah0 = *reinterpret_cast<const bf16x8*>(kt + ro + o0);
      const bf16x8 ah1 = *reinterpret_cast<const bf16x8*>(kt + ro + o1);
      f32x4 acc0 = {0.f, 0.f, 0.f, 0.f};
      f32x4 acc1 = {0.f, 0.f, 0.f, 0.f};
      acc0 = __builtin_amdgcn_mfma_f32_16x16x32_bf16(ah0, q0h0, acc0, 0, 0, 0);
      acc1 = __builtin_amdgcn_mfma_f32_16x16x32_bf16(ah0, q1h0, acc1, 0, 0, 0);
      acc0 = __builtin_amdgcn_mfma_f32_16x16x32_bf16(ah1, q0h1, acc0, 0, 0, 0);
      acc1 = __builtin_amdgcn_mfma_f32_16x16x32_bf16(ah1, q1h1, acc1, 0, 0, 0);

      // per-query step max (4 key-lane groups) -> running max incl. current
      float s40 = fmaxf(fmaxf(acc0[0], acc0[1]), fmaxf(acc0[2], acc0[3]));
      float s41 = fmaxf(fmaxf(acc1[0], acc1[1]), fmaxf(acc1[2], acc1[3]));
      float g0 = fmaxf(s40, __shfl_xor(s40, 16, 64));
      g0 = fmaxf(g0, __shfl_xor(g0, 32, 64));
      float g1 = fmaxf(s41, __shfl_xor(s41, 16, 64));
      g1 = fmaxf(g1, __shfl_xor(g1, 32, 64));
      m0 = fmaxf(m0, g0);
      m1 = fmaxf(m1, g1);

      const int kb = kbase + t * KT + s * 16 + lg * 4;   // C/D: row=(lane>>4)*4+reg
      const float gt0 = m0 - DGATE;
      if (s40 > gt0) {
        if (acc0[0] > gt0) emit(acc0[0], kb,     qi0);
        if (acc0[1] > gt0) emit(acc0[1], kb + 1, qi0);
        if (acc0[2] > gt0) emit(acc0[2], kb + 2, qi0);
        if (acc0[3] > gt0) emit(acc0[3], kb + 3, qi0);
      }
      const float gt1 = m1 - DGATE;
      if (s41 > gt1) {
        if (acc1[0] > gt1) emit(acc1[0], kb,     qi1);
        if (acc1[1] > gt1) emit(acc1[1], kb + 1, qi1);
        if (acc1[2] > gt1) emit(acc1[2], kb + 2, qi1);
        if (acc1[3] > gt1) emit(acc1[3], kb + 3, qi1);
      }
    }
    __syncthreads();
  }
}

// ==== merge: top-9 by hi, exact fp32 rescore of finalists, softmax, V gather =
__global__ __launch_bounds__(256) void merge_v(
    const float2* __restrict__ Cand, const int* __restrict__ Cnt,
    const float* __restrict__ qg, const float* __restrict__ Kt,
    const float* __restrict__ Vt, float* __restrict__ Og) {
  __shared__ float Wls[128][K9];
  __shared__ int   Ils[128][K9];
  const int tid = threadIdx.x, b = blockIdx.y, qbase = blockIdx.x * 128;

  if (tid < 128) {
    const int n  = qbase + tid;
    const int qi = b * NPIX + n;
    const int c = min(Cnt[qi], CAP);
    const float2* cp = Cand + (size_t)qi * CAP;

    // pass 1: top-9 by hi-score
    float tv[K9]; int ti[K9];
    #pragma unroll
    for (int r = 0; r < K9; ++r) { tv[r] = -3.4e38f; ti[r] = 0x7fffffff; }
    for (int j = 0; j < c; ++j) {
      const float2 e = cp[j];
      const int i = __float_as_int(e.y);
      if (e.x > tv[8] || (e.x == tv[8] && i < ti[8])) ins9t(tv, ti, e.x, i);
    }
    const float thr = tv[8] - THRM;

    // q-hat row (x8), lane-coalesced strided loads from original [b][d][n]
    float qr[HD];
    #pragma unroll
    for (int d = 0; d < HD; ++d)
      qr[d] = 8.f * qg[((size_t)b * HD + d) * NPIX + n];

    // pass 2: exact fp32 rescore for cands with hi >= thr
    float ev[K9]; int ei[K9];
    #pragma unroll
    for (int r = 0; r < K9; ++r) { ev[r] = -3.4e38f; ei[r] = 0x7fffffff; }
    for (int j = 0; j < c; ++j) {
      const float2 e = cp[j];
      if (e.x < thr) continue;
      const int i = __float_as_int(e.y);
      const float4* kr = reinterpret_cast<const float4*>(Kt + ((size_t)b * NPIX + i) * HD);
      float acc = 0.f;
      #pragma unroll
      for (int u = 0; u < 16; ++u) {
        const float4 kx = kr[u];
        acc = fmaf(qr[u * 4],     kx.x, acc);
        acc = fmaf(qr[u * 4 + 1], kx.y, acc);
        acc = fmaf(qr[u * 4 + 2], kx.z, acc);
        acc = fmaf(qr[u * 4 + 3], kx.w, acc);
      }
      if (acc > ev[8] || (acc == ev[8] && i < ei[8])) ins9t(ev, ei, acc, i);
    }

    const float mmax = ev[0];
    float ex[K9]; float ssum = 0.f;
    #pragma unroll
    for (int r = 0; r < K9; ++r) { ex[r] = expf(ev[r] - mmax); ssum += ex[r]; }
    const float inv = 1.f / ssum;
    #pragma unroll
    for (int r = 0; r < K9; ++r) {
      Wls[tid][r] = ex[r] * inv;
      Ils[tid][r] = (ev[r] > -1e38f) ? ei[r] : 0;   // weight 0 -> safe idx
    }
  }
  __syncthreads();

  // V gather: 2 threads per query, 32 dims each; Vt rows contiguous 256 B
  {
    const int q = tid >> 1, half = tid & 1;
    float o[32];
    #pragma unroll
    for (int c2 = 0; c2 < 32; ++c2) o[c2] = 0.f;
    #pragma unroll
    for (int r = 0; r < K9; ++r) {
      const float wgt = Wls[q][r];
      const int   m   = Ils[q][r];
      const float4* vp = reinterpret_cast<const float4*>(
          Vt + ((size_t)b * NPIX + m) * HD + half * 32);
      #pragma unroll
      for (int c4 = 0; c4 < 8; ++c4) {
        const float4 vv = vp[c4];
        o[c4 * 4]     = fmaf(wgt, vv.x, o[c4 * 4]);
        o[c4 * 4 + 1] = fmaf(wgt, vv.y, o[c4 * 4 + 1]);
        o[c4 * 4 + 2] = fmaf(wgt, vv.z, o[c4 * 4 + 2]);
        o[c4 * 4 + 3] = fmaf(wgt, vv.w, o[c4 * 4 + 3]);
      }
    }
    float* op = Og + (((size_t)b * NPIX) + qbase + q) * HD + half * 32;
    #pragma unroll
    for (int c4 = 0; c4 < 8; ++c4)
      *reinterpret_cast<float4*>(op + c4 * 4) =
        make_float4(o[c4 * 4], o[c4 * 4 + 1], o[c4 * 4 + 2], o[c4 * 4 + 3]);
  }
}

// ================= launch =====================================================
extern "C" void kernel_launch(void* const* d_in, const int* in_sizes, int n_in,
                              void* d_out, int out_size, void* d_ws, size_t ws_size,
                              hipStream_t stream) {
  const float* q = (const float*)d_in[0];
  const float* k = (const float*)d_in[1];
  const float* v = (const float*)d_in[2];
  float* o = (float*)d_out;

  const size_t asz = (size_t)B4 * NPIX * HD;          // 2.36M elems per array
  const int nq = B4 * NPIX;
  ushort_t* Qbf = (ushort_t*)d_ws;                    // 4.72 MB
  ushort_t* Kbf = Qbf + asz;                          // 4.72 MB
  float*    Kt  = (float*)(Kbf + asz);                // 9.44 MB
  float*    Vt  = Kt + asz;                           // 9.44 MB
  float*    Pm  = Vt + asz;                           // 0.29 MB  [qi][2]
  int*      Ct  = (int*)(Pm + (size_t)nq * SSL);      // 0.15 MB
  float2*   Cd  = (float2*)(Ct + nq);                 // 23.6 MB  [qi][CAP]

  hipMemsetAsync(Ct, 0, (size_t)nq * sizeof(int), stream);
  prep_kernel<<<dim3(NPIX / 64, B4, 3), 256, 0, stream>>>(q, k, v, Qbf, Kbf, Kt, Vt);
  pass_sample<<<dim3(NPIX / QBLK, B4, SSL), 256, 0, stream>>>(Qbf, Kbf, Pm);
  pass_gate<<<dim3(NPIX / QBLK, B4, ZS), 256, 0, stream>>>(Qbf, Kbf, Pm, Ct, Cd);
  merge_v<<<dim3(NPIX / 128, B4), 256, 0, stream>>>(Cd, Ct, q, Kt, Vt, o);
}